// Round 4
// baseline (136.492 us; speedup 1.0000x reference)
//
#include <hip/hip_runtime.h>
#include <math.h>

// NoiseGenerator: out[n][b] = (y1[n][b] - y2[n][b]) * env[n][b]   (gain folded into y)
//   y1[n] = f_lp*y1[n-1] + (1-f_lp)*gain*noise[n]
//   y2[n] = f_hp*y2[n-1] + (1-f_hp)*y1[n]          (highpass = y1 - y2)
//   env[n] = (1 - exp(-t/(attack+eps))) * exp(-t/(decay+eps)), t = n/48000
//
// Group-scan structure (thread owns a 100-sample serial run):
//   kA: thread (g, 2 cols) runs samples [g*100, g*100+100) from zero state,
//       writes ONLY the group aggregate (2 floats/col). ws = 2 MB.
//   kB: per-column serial scan over 240 group aggregates with multiplier
//       M^100 (cancellation-safe homogeneous recurrence). 16 blocks x 64 so
//       the scan traffic spreads over 16 CUs.
//   kC: thread (g, 2 cols) re-runs its 100 samples from the exact entry
//       state, applies the envelope incrementally (re-anchored per group),
//       streams float2 stores (8B/lane, 512B/wave/row).

#define NSAMP   24000
#define NBATCH  1024
#define SPT     100            // samples per thread (group length)
#define NGRP    240            // NSAMP / SPT
#define CPT     2              // columns per thread -> float2 stores
#define TPB     256
#define NCOLG   (NBATCH/(TPB*CPT))   // 2 column-groups
#define EPSF    1e-4f
#define DT      (1.0f/48000.0f)

// ---------------- Phase A: group aggregates (zero entry state) ----------------
__global__ __launch_bounds__(TPB) void kA_aggr(const float* __restrict__ par,
                                               const float* __restrict__ noise,
                                               float* __restrict__ gv1,
                                               float* __restrict__ gv2) {
    const int g    = blockIdx.x;
    const int col0 = blockIdx.y * (TPB * CPT) + threadIdx.x * CPT;
    const int n0   = g * SPT;

    float a1[CPT], c1[CPT], a2[CPT], c2[CPT], y1[CPT], y2[CPT];
#pragma unroll
    for (int k = 0; k < CPT; ++k) {
        const int b = col0 + k;
        a1[k] = par[2 * NBATCH + b];                 // f_lp
        a2[k] = par[3 * NBATCH + b];                 // f_hp
        const float g_ = par[4 * NBATCH + b];        // gain
        c1[k] = (1.0f - a1[k]) * g_;                 // gain folded in (matches kC)
        c2[k] = 1.0f - a2[k];
        y1[k] = 0.0f; y2[k] = 0.0f;
    }

#pragma unroll 4
    for (int i = 0; i < SPT; ++i) {
        const float x = noise[n0 + i];               // block-uniform -> s_load
#pragma unroll
        for (int k = 0; k < CPT; ++k) {
            y1[k] = a1[k] * y1[k] + c1[k] * x;
            y2[k] = a2[k] * y2[k] + c2[k] * y1[k];
        }
    }
    *reinterpret_cast<float2*>(&gv1[g * NBATCH + col0]) = make_float2(y1[0], y1[1]);
    *reinterpret_cast<float2*>(&gv2[g * NBATCH + col0]) = make_float2(y2[0], y2[1]);
}

// ---------------- Phase B: per-column serial scan over groups ----------------
__global__ __launch_bounds__(64) void kB_scan(const float* __restrict__ par,
                                              float* __restrict__ gv1,
                                              float* __restrict__ gv2) {
    const int b = blockIdx.x * 64 + threadIdx.x;     // 16 blocks x 64 = 1024 cols
    const float a1 = par[2 * NBATCH + b];
    const float a2 = par[3 * NBATCH + b];
    const float c2 = 1.0f - a2;

    // M^SPT via homogeneous recurrence (cancellation-safe when f_lp ~ f_hp):
    float u1 = 1.0f, u2 = 0.0f, u3 = 1.0f;
#pragma unroll 4
    for (int i = 0; i < SPT; ++i) {
        u1 = a1 * u1;
        u2 = a2 * u2 + c2 * u1;
        u3 = a2 * u3;
    }
    const float p1 = u1, mL = u2, p2 = u3;

    float s1 = 0.0f, s2 = 0.0f;                      // entry state of group 0
#pragma unroll 4
    for (int c = 0; c < NGRP; ++c) {
        const float v1 = gv1[c * NBATCH + b];
        const float v2 = gv2[c * NBATCH + b];
        gv1[c * NBATCH + b] = s1;                    // overwrite aggregate with entry
        gv2[c * NBATCH + b] = s2;
        const float w  = mL * s1 + v2;               // off the s2 critical chain
        s1 = p1 * s1 + v1;                           // two 4-cyc chains
        s2 = p2 * s2 + w;
    }
}

// ---------------- Phase C: output pass with envelope ----------------
__global__ __launch_bounds__(TPB) void kC_out(const float* __restrict__ par,
                                              const float* __restrict__ noise,
                                              const float* __restrict__ gv1,
                                              const float* __restrict__ gv2,
                                              float* __restrict__ out) {
    const int g    = blockIdx.x;
    const int col0 = blockIdx.y * (TPB * CPT) + threadIdx.x * CPT;
    const int n0   = g * SPT;

    float a1[CPT], c1[CPT], a2[CPT], c2[CPT], y1[CPT], y2[CPT];
    float ea[CPT], ra[CPT], ed[CPT], rd[CPT];
    const float t0 = (float)n0 * DT;

    const float2 e1 = *reinterpret_cast<const float2*>(&gv1[g * NBATCH + col0]);
    const float2 e2 = *reinterpret_cast<const float2*>(&gv2[g * NBATCH + col0]);
    y1[0] = e1.x; y1[1] = e1.y;
    y2[0] = e2.x; y2[1] = e2.y;

#pragma unroll
    for (int k = 0; k < CPT; ++k) {
        const int b = col0 + k;
        const float ia  = 1.0f / (par[b] + EPSF);              // attack
        const float idc = 1.0f / (par[NBATCH + b] + EPSF);     // decay
        a1[k] = par[2 * NBATCH + b];
        a2[k] = par[3 * NBATCH + b];
        const float g_ = par[4 * NBATCH + b];
        c1[k] = (1.0f - a1[k]) * g_;
        c2[k] = 1.0f - a2[k];
        ea[k] = expf(-t0 * ia);   ra[k] = expf(-DT * ia);      // re-anchored per group;
        ed[k] = expf(-t0 * idc);  rd[k] = expf(-DT * idc);     // drift ~ SPT ulps, tiny
    }

    float2* op = reinterpret_cast<float2*>(out + (size_t)n0 * NBATCH + col0);
#pragma unroll 4
    for (int i = 0; i < SPT; ++i) {
        const float x = noise[n0 + i];               // block-uniform -> s_load
        float2 o;
#pragma unroll
        for (int k = 0; k < CPT; ++k) {
            y1[k] = a1[k] * y1[k] + c1[k] * x;
            y2[k] = a2[k] * y2[k] + c2[k] * y1[k];
            const float env = (1.0f - ea[k]) * ed[k];
            (&o.x)[k] = (y1[k] - y2[k]) * env;
            ea[k] *= ra[k];
            ed[k] *= rd[k];
        }
        *op = o;                                     // 8B/lane coalesced row store
        op += NBATCH / 2;
    }
}

extern "C" void kernel_launch(void* const* d_in, const int* in_sizes, int n_in,
                              void* d_out, int out_size, void* d_ws, size_t ws_size,
                              hipStream_t stream) {
    const float* par   = (const float*)d_in[0];   // [5, 1024]
    const float* noise = (const float*)d_in[1];   // [24000]
    float* out = (float*)d_out;                   // [24000, 1024]
    float* gv1 = (float*)d_ws;                    // [NGRP][NBATCH]
    float* gv2 = gv1 + (size_t)NGRP * NBATCH;     // [NGRP][NBATCH]  (~2 MB total)

    kA_aggr<<<dim3(NGRP, NCOLG), dim3(TPB), 0, stream>>>(par, noise, gv1, gv2);
    kB_scan<<<dim3(16), dim3(64), 0, stream>>>(par, gv1, gv2);
    kC_out <<<dim3(NGRP, NCOLG), dim3(TPB), 0, stream>>>(par, noise, gv1, gv2, out);
}

// Round 7
// 128.216 us; speedup vs baseline: 1.0645x; 1.0645x over previous
//
#include <hip/hip_runtime.h>
#include <math.h>

// NoiseGenerator: out[n][b] = (y1[n][b] - y2[n][b]) * env[n][b]   (gain folded into y)
//   y1[n] = f_lp*y1[n-1] + (1-f_lp)*gain*noise[n]
//   y2[n] = f_hp*y2[n-1] + (1-f_hp)*y1[n]          (highpass = y1 - y2)
//   env[n] = (1 - exp(-t/(attack+eps))) * exp(-t/(decay+eps)), t = n/48000
//
// Group-scan, round 7:
//   SPT=50 -> 480 groups: kA/kC run 480 blocks (~1.9 waves/SIMD, vs 0.94 at
//   SPT=100/CPT=4) while keeping float4 stores (16B/lane).
//   kA: thread (g, 4 cols) runs its 50 samples from zero state, writes the
//       group aggregate only. ws = 4 MB.
//   kB: LDS-staged scan — 64 blocks x 16 cols stage [480][16] x2 into LDS
//       (61.4 KB, conflict-free), 16 threads/block scan from LDS, write
//       entry states back. No latency-serialized global walk.
//   kC: thread (g, 4 cols) re-runs its 50 samples from the exact entry
//       state, envelope via incremental exp (re-anchored per group),
//       float4 streaming stores.

#define NSAMP   24000
#define NBATCH  1024
#define SPT     50             // samples per thread (group length)
#define NGRP    480            // NSAMP / SPT
#define CPT     4              // columns per thread -> float4 stores
#define TPB     256            // 256*4 = 1024 cols -> one block spans all columns
#define EPSF    1e-4f
#define DT      (1.0f/48000.0f)

// ---------------- Phase A: group aggregates (zero entry state) ----------------
__global__ __launch_bounds__(TPB) void kA_aggr(const float* __restrict__ par,
                                               const float* __restrict__ noise,
                                               float* __restrict__ gv1,
                                               float* __restrict__ gv2) {
    const int g    = blockIdx.x;
    const int col0 = threadIdx.x * CPT;
    const int n0   = g * SPT;

    const float4 flp = *reinterpret_cast<const float4*>(&par[2 * NBATCH + col0]);
    const float4 fhp = *reinterpret_cast<const float4*>(&par[3 * NBATCH + col0]);
    const float4 gn  = *reinterpret_cast<const float4*>(&par[4 * NBATCH + col0]);

    float a1[CPT], c1[CPT], a2[CPT], c2[CPT], y1[CPT], y2[CPT];
#pragma unroll
    for (int k = 0; k < CPT; ++k) {
        a1[k] = (&flp.x)[k];
        a2[k] = (&fhp.x)[k];
        c1[k] = (1.0f - a1[k]) * (&gn.x)[k];         // gain folded in (matches kC)
        c2[k] = 1.0f - a2[k];
        y1[k] = 0.0f; y2[k] = 0.0f;
    }

#pragma unroll 10
    for (int i = 0; i < SPT; ++i) {
        const float x = noise[n0 + i];               // block-uniform -> s_load
#pragma unroll
        for (int k = 0; k < CPT; ++k) {
            y1[k] = a1[k] * y1[k] + c1[k] * x;
            y2[k] = a2[k] * y2[k] + c2[k] * y1[k];
        }
    }
    *reinterpret_cast<float4*>(&gv1[g * NBATCH + col0]) = make_float4(y1[0], y1[1], y1[2], y1[3]);
    *reinterpret_cast<float4*>(&gv2[g * NBATCH + col0]) = make_float4(y2[0], y2[1], y2[2], y2[3]);
}

// ---------------- Phase B: LDS-staged per-column scan over groups ----------------
#define KB_COLS 16             // columns per block; LDS = 480*16*4*2 = 61.4 KB
__global__ __launch_bounds__(256) void kB_scan(const float* __restrict__ par,
                                               float* __restrict__ gv1,
                                               float* __restrict__ gv2) {
    __shared__ float l1[NGRP][KB_COLS];
    __shared__ float l2[NGRP][KB_COLS];
    const int col0 = blockIdx.x * KB_COLS;           // 64 blocks
    const int j    = threadIdx.x & (KB_COLS - 1);
    const int r0   = threadIdx.x >> 4;               // 16 rows per pass

    // stage: throughput-bound, 256 threads, independent loads;
    // wave = 4 rows x 16 cols = 64 consecutive words -> 2 lanes/bank (free)
#pragma unroll 5
    for (int r = r0; r < NGRP; r += 16) {
        l1[r][j] = gv1[r * NBATCH + col0 + j];
        l2[r][j] = gv2[r * NBATCH + col0 + j];
    }
    __syncthreads();

    if (threadIdx.x < KB_COLS) {
        const int b = col0 + j;
        const float a1 = par[2 * NBATCH + b];
        const float a2 = par[3 * NBATCH + b];
        const float c2 = 1.0f - a2;

        // M^SPT via homogeneous recurrence (cancellation-safe when f_lp ~ f_hp):
        float u1 = 1.0f, u2 = 0.0f, u3 = 1.0f;
#pragma unroll 10
        for (int i = 0; i < SPT; ++i) {
            u1 = a1 * u1;
            u2 = a2 * u2 + c2 * u1;
            u3 = a2 * u3;
        }
        const float p1 = u1, mL = u2, p2 = u3;

        float s1 = 0.0f, s2 = 0.0f;                  // entry state of group 0
#pragma unroll 8
        for (int c = 0; c < NGRP; ++c) {
            const float v1 = l1[c][j];
            const float v2 = l2[c][j];
            l1[c][j] = s1;                           // overwrite aggregate with entry
            l2[c][j] = s2;
            const float w  = mL * s1 + v2;           // off the s2 critical chain
            s1 = p1 * s1 + v1;                       // two short FMA chains
            s2 = p2 * s2 + w;
        }
    }
    __syncthreads();

    // writeback entry states
#pragma unroll 5
    for (int r = r0; r < NGRP; r += 16) {
        gv1[r * NBATCH + col0 + j] = l1[r][j];
        gv2[r * NBATCH + col0 + j] = l2[r][j];
    }
}

// ---------------- Phase C: output pass with envelope ----------------
__global__ __launch_bounds__(TPB) void kC_out(const float* __restrict__ par,
                                              const float* __restrict__ noise,
                                              const float* __restrict__ gv1,
                                              const float* __restrict__ gv2,
                                              float* __restrict__ out) {
    const int g    = blockIdx.x;
    const int col0 = threadIdx.x * CPT;
    const int n0   = g * SPT;

    const float4 att4 = *reinterpret_cast<const float4*>(&par[0 * NBATCH + col0]);
    const float4 dec4 = *reinterpret_cast<const float4*>(&par[1 * NBATCH + col0]);
    const float4 flp  = *reinterpret_cast<const float4*>(&par[2 * NBATCH + col0]);
    const float4 fhp  = *reinterpret_cast<const float4*>(&par[3 * NBATCH + col0]);
    const float4 gn   = *reinterpret_cast<const float4*>(&par[4 * NBATCH + col0]);
    const float4 e1   = *reinterpret_cast<const float4*>(&gv1[g * NBATCH + col0]);
    const float4 e2   = *reinterpret_cast<const float4*>(&gv2[g * NBATCH + col0]);

    float a1[CPT], c1[CPT], a2[CPT], c2[CPT], y1[CPT], y2[CPT];
    float ea[CPT], ra[CPT], ed[CPT], rd[CPT];
    const float t0 = (float)n0 * DT;

#pragma unroll
    for (int k = 0; k < CPT; ++k) {
        const float ia  = 1.0f / ((&att4.x)[k] + EPSF);
        const float idc = 1.0f / ((&dec4.x)[k] + EPSF);
        a1[k] = (&flp.x)[k];
        a2[k] = (&fhp.x)[k];
        c1[k] = (1.0f - a1[k]) * (&gn.x)[k];
        c2[k] = 1.0f - a2[k];
        ea[k] = expf(-t0 * ia);   ra[k] = expf(-DT * ia);   // re-anchored per group;
        ed[k] = expf(-t0 * idc);  rd[k] = expf(-DT * idc);  // drift ~ SPT ulps, tiny
        y1[k] = (&e1.x)[k];                                 // exact entry state
        y2[k] = (&e2.x)[k];
    }

    float4* op = reinterpret_cast<float4*>(out + (size_t)n0 * NBATCH + col0);
#pragma unroll 5
    for (int i = 0; i < SPT; ++i) {
        const float x = noise[n0 + i];               // block-uniform -> s_load
        float4 o;
#pragma unroll
        for (int k = 0; k < CPT; ++k) {
            y1[k] = a1[k] * y1[k] + c1[k] * x;
            y2[k] = a2[k] * y2[k] + c2[k] * y1[k];
            const float env = (1.0f - ea[k]) * ed[k];
            (&o.x)[k] = (y1[k] - y2[k]) * env;
            ea[k] *= ra[k];
            ed[k] *= rd[k];
        }
        *op = o;                                     // 16B/lane, 1KB/wave coalesced
        op += NBATCH / 4;
    }
}

extern "C" void kernel_launch(void* const* d_in, const int* in_sizes, int n_in,
                              void* d_out, int out_size, void* d_ws, size_t ws_size,
                              hipStream_t stream) {
    const float* par   = (const float*)d_in[0];   // [5, 1024]
    const float* noise = (const float*)d_in[1];   // [24000]
    float* out = (float*)d_out;                   // [24000, 1024]
    float* gv1 = (float*)d_ws;                    // [NGRP][NBATCH]
    float* gv2 = gv1 + (size_t)NGRP * NBATCH;     // [NGRP][NBATCH]  (~4 MB total)

    kA_aggr<<<dim3(NGRP), dim3(TPB), 0, stream>>>(par, noise, gv1, gv2);
    kB_scan<<<dim3(NBATCH / KB_COLS), dim3(256), 0, stream>>>(par, gv1, gv2);
    kC_out <<<dim3(NGRP), dim3(TPB), 0, stream>>>(par, noise, gv1, gv2, out);
}